// Round 1
// baseline (298.525 us; speedup 1.0000x reference)
//
#include <hip/hip_runtime.h>

// Problem constants (match reference)
#define RREL 8
#define COUT 4
#define NEDGE 2000000
#define E4   (NEDGE / 4)      // 500,000 float4 per relation
#define N4   (RREL * E4)      // 4,000,000 float4 total in edge_w

// ---------------------------------------------------------------------------
// Kernel 1: compute Filter = softmax(weight, axis=1)  [C, R] and write it to
// the Filter output slot (d_out + C*R*E). One block, first COUT threads each
// handle one row of 8.
// ---------------------------------------------------------------------------
__global__ void gtconv_filter_kernel(const float* __restrict__ weight,
                                     float* __restrict__ filter_out) {
    int c = threadIdx.x;
    if (c < COUT) {
        float v[RREL];
        float m = -3.402823e38f;
        #pragma unroll
        for (int r = 0; r < RREL; ++r) {
            v[r] = weight[c * RREL + r];
            m = fmaxf(m, v[r]);
        }
        float s = 0.0f;
        #pragma unroll
        for (int r = 0; r < RREL; ++r) {
            v[r] = expf(v[r] - m);
            s += v[r];
        }
        float inv = 1.0f / s;
        #pragma unroll
        for (int r = 0; r < RREL; ++r) {
            filter_out[c * RREL + r] = v[r] * inv;
        }
    }
}

// ---------------------------------------------------------------------------
// Kernel 2: out[c,r,e] = Filter[c,r] * edge_w[r,e].
// One thread per float4 of edge_w: 1 coalesced 16B load, 4 coalesced 16B
// stores (one per output channel). edge_w is read from HBM exactly once.
// ---------------------------------------------------------------------------
__global__ void __launch_bounds__(256)
gtconv_scale_kernel(const float4* __restrict__ ew4,
                    const float* __restrict__ filter,   // [C*R], from kernel 1
                    float4* __restrict__ out4) {
    __shared__ float sf[COUT * RREL];
    if (threadIdx.x < COUT * RREL) sf[threadIdx.x] = filter[threadIdx.x];
    __syncthreads();

    int idx = blockIdx.x * blockDim.x + threadIdx.x;
    if (idx >= N4) return;

    int r = idx / E4;                 // relation index (compiler magic-mul)
    float4 w = ew4[idx];

    #pragma unroll
    for (int c = 0; c < COUT; ++c) {
        float f = sf[c * RREL + r];
        float4 o;
        o.x = w.x * f;
        o.y = w.y * f;
        o.z = w.z * f;
        o.w = w.w * f;
        out4[(size_t)c * N4 + idx] = o;
    }
}

extern "C" void kernel_launch(void* const* d_in, const int* in_sizes, int n_in,
                              void* d_out, int out_size, void* d_ws, size_t ws_size,
                              hipStream_t stream) {
    const float* edge_w = (const float*)d_in[0];   // [R, E] f32
    const float* weight = (const float*)d_in[1];   // [C, R] f32
    float* out = (float*)d_out;                    // [C*R*E] out + [C*R] Filter

    float* filter_slot = out + (size_t)COUT * RREL * NEDGE;  // second tuple element

    // 1) Filter = softmax(weight, axis=1) -> written to output tail
    gtconv_filter_kernel<<<1, 64, 0, stream>>>(weight, filter_slot);

    // 2) Broadcast-scale edge weights into the [C,R,E] output
    int blocks = (N4 + 255) / 256;
    gtconv_scale_kernel<<<blocks, 256, 0, stream>>>(
        (const float4*)edge_w, filter_slot, (float4*)out);
}

// Round 3
// 293.454 us; speedup vs baseline: 1.0173x; 1.0173x over previous
//
#include <hip/hip_runtime.h>

// Problem constants (match reference)
#define RREL 8
#define COUT 4
#define NEDGE 2000000
#define E4   (NEDGE / 4)      // 500,000 float4 per relation
#define N4   (RREL * E4)      // 4,000,000 float4 total in edge_w
#define BLOCK 256
#define GRID  (N4 / BLOCK)    // 15625, exact — no tail check needed

// Native vector type — __builtin_nontemporal_* requires a true vector,
// not HIP's float4 class wrapper.
typedef float vfloat4 __attribute__((ext_vector_type(4)));

// ---------------------------------------------------------------------------
// Fused kernel: every block redundantly computes the 4x8 softmax from
// `weight` (128 B, L2-broadcast — cheap), then scales its slice of edge_w
// into the 4 output channels. Block 0 also writes the Filter tuple output.
// One thread per float4 of edge_w: 1 NT 16B load, 4 NT 16B stores.
// ---------------------------------------------------------------------------
__global__ void __launch_bounds__(BLOCK)
gtconv_fused_kernel(const vfloat4* __restrict__ ew4,
                    const float* __restrict__ weight,   // [C, R]
                    vfloat4* __restrict__ out4,         // [C, R*E/4]
                    float* __restrict__ filter_out) {   // [C, R] tuple elem 1
    __shared__ float sf[COUT * RREL];

    int t = threadIdx.x;
    if (t < COUT) {
        // Thread t computes softmax row t (8 elements) serially.
        float v[RREL];
        float m = -3.402823e38f;
        #pragma unroll
        for (int r = 0; r < RREL; ++r) {
            v[r] = weight[t * RREL + r];
            m = fmaxf(m, v[r]);
        }
        float s = 0.0f;
        #pragma unroll
        for (int r = 0; r < RREL; ++r) {
            v[r] = __expf(v[r] - m);
            s += v[r];
        }
        float inv = 1.0f / s;
        #pragma unroll
        for (int r = 0; r < RREL; ++r) {
            float f = v[r] * inv;
            sf[t * RREL + r] = f;
            if (blockIdx.x == 0) filter_out[t * RREL + r] = f;
        }
    }
    __syncthreads();

    int idx = blockIdx.x * BLOCK + t;     // < N4 exactly, no tail
    int r = idx / E4;                     // relation index (magic-mul)

    vfloat4 w = __builtin_nontemporal_load(&ew4[idx]);

    #pragma unroll
    for (int c = 0; c < COUT; ++c) {
        float f = sf[c * RREL + r];
        vfloat4 o = w * f;
        __builtin_nontemporal_store(o, &out4[(size_t)c * N4 + idx]);
    }
}

extern "C" void kernel_launch(void* const* d_in, const int* in_sizes, int n_in,
                              void* d_out, int out_size, void* d_ws, size_t ws_size,
                              hipStream_t stream) {
    const float* edge_w = (const float*)d_in[0];   // [R, E] f32
    const float* weight = (const float*)d_in[1];   // [C, R] f32
    float* out = (float*)d_out;                    // [C*R*E] out ++ [C*R] Filter

    float* filter_slot = out + (size_t)COUT * RREL * NEDGE;

    gtconv_fused_kernel<<<GRID, BLOCK, 0, stream>>>(
        (const vfloat4*)edge_w, weight, (vfloat4*)out, filter_slot);
}